// Round 9
// baseline (201.787 us; speedup 1.0000x reference)
//
#include <hip/hip_runtime.h>
#include <stdint.h>

typedef unsigned long long u64;
typedef unsigned int u32;

#define T_STEPS 64
#define KDIM 784
#define N1 1024
#define NB 2048
#define N2 10

// ---------------- K0: fused prep: transposes X->Xt, W1->W1t, and W2->W2T ----------------
// blocks 0..1599: X tiles; 1600..2399: W1 tiles; 2400: W2T.
__global__ __launch_bounds__(256) void k_prep(
    const float* __restrict__ X, float* __restrict__ Xt,
    const float* __restrict__ W1, float* __restrict__ W1t,
    const float* __restrict__ W2, float* __restrict__ W2T)
{
    int b = blockIdx.x;
    if (b == 2400) {                     // W2 [10][1024] -> W2T [1024][12]
        for (int it = 0; it < 4; ++it) {
            int j = it * 256 + threadIdx.x;
            float r[12];
#pragma unroll
            for (int i = 0; i < 10; ++i) r[i] = W2[i * N1 + j];
            r[10] = 0.f; r[11] = 0.f;
#pragma unroll
            for (int i = 0; i < 12; ++i) W2T[j * 12 + i] = r[i];
        }
        return;
    }
    __shared__ float t[32][33];
    const float* src; float* dst; int R;
    int tile_r, tile_c;
    if (b < 1600) { src = X;  dst = Xt;  R = NB; tile_r = b / 25; tile_c = b % 25; }
    else { b -= 1600; src = W1; dst = W1t; R = N1; tile_r = b / 25; tile_c = b % 25; }

    const int tx = threadIdx.x & 31, ty = threadIdx.x >> 5;
    const int r0 = tile_r << 5, c0 = tile_c << 5;

#pragma unroll
    for (int i = 0; i < 32; i += 8) {
        int c = c0 + tx;
        t[ty + i][tx] = (c < KDIM) ? src[(size_t)(r0 + ty + i) * KDIM + c] : 0.f;
    }
    __syncthreads();
#pragma unroll
    for (int i = 0; i < 32; i += 8) {
        int c = c0 + ty + i;
        if (c < KDIM) dst[(size_t)c * R + r0 + tx] = t[tx][ty + i];
    }
}

// ---------------- K1: c1 = X @ W1^T (fp32), LDS-free register pipeline, fused LIF-1 ----
// 64x64 tile, 256 threads, 4x4/thread. Per kk: av = 16B of Xt row-k (quarter-wave
// broadcast), bv = 16B of W1t row-k (contiguous 256B/wave). Modulo-scheduled with
// depth-16 register prefetch (pa/pb), zero barriers, zero LDS.
// FMA order: k ascending, strictly sequential per acc -> c1 bit-identical.
__global__ __launch_bounds__(256, 2) void k_gemm_lif1(
    const float* __restrict__ Xt,    // [784][2048]
    const float* __restrict__ W1t,   // [784][1024]
    u64* __restrict__ bits)
{
    const int tid = threadIdx.x;
    const int tx  = tid & 15;             // n-group
    const int ty  = tid >> 4;             // m-group (0..15)
    const int bm  = blockIdx.y << 6;
    const int bn  = blockIdx.x << 6;

#define LOAD_A(k) (*(const float4*)(Xt  + (size_t)(k) * NB + bm + (ty << 2)))
#define LOAD_B(k) (*(const float4*)(W1t + (size_t)(k) * N1 + bn + (tx << 2)))
#define FMAS(av, bv)                                                                      \
    acc[0][0] = fmaf(av.x, bv.x, acc[0][0]); acc[0][1] = fmaf(av.x, bv.y, acc[0][1]);     \
    acc[0][2] = fmaf(av.x, bv.z, acc[0][2]); acc[0][3] = fmaf(av.x, bv.w, acc[0][3]);     \
    acc[1][0] = fmaf(av.y, bv.x, acc[1][0]); acc[1][1] = fmaf(av.y, bv.y, acc[1][1]);     \
    acc[1][2] = fmaf(av.y, bv.z, acc[1][2]); acc[1][3] = fmaf(av.y, bv.w, acc[1][3]);     \
    acc[2][0] = fmaf(av.z, bv.x, acc[2][0]); acc[2][1] = fmaf(av.z, bv.y, acc[2][1]);     \
    acc[2][2] = fmaf(av.z, bv.z, acc[2][2]); acc[2][3] = fmaf(av.z, bv.w, acc[2][3]);     \
    acc[3][0] = fmaf(av.w, bv.x, acc[3][0]); acc[3][1] = fmaf(av.w, bv.y, acc[3][1]);     \
    acc[3][2] = fmaf(av.w, bv.z, acc[3][2]); acc[3][3] = fmaf(av.w, bv.w, acc[3][3]);

    float acc[4][4];
#pragma unroll
    for (int r = 0; r < 4; ++r)
#pragma unroll
        for (int c = 0; c < 4; ++c) acc[r][c] = 0.f;

    float4 pa[16], pb[16];
#pragma unroll
    for (int q = 0; q < 16; ++q) { pa[q] = LOAD_A(q); pb[q] = LOAD_B(q); }

    for (int t = 0; t < 48; ++t) {       // 784 = 49*16; prefetch next 16-kk group
#pragma unroll
        for (int q = 0; q < 16; ++q) {
            float4 av = pa[q], bv = pb[q];
            pa[q] = LOAD_A(t * 16 + 16 + q);
            pb[q] = LOAD_B(t * 16 + 16 + q);
            FMAS(av, bv);
        }
    }
#pragma unroll
    for (int q = 0; q < 16; ++q) {       // peeled last group, no prefetch
        float4 av = pa[q], bv = pb[q];
        FMAS(av, bv);
    }
#undef LOAD_A
#undef LOAD_B
#undef FMAS

    // LIF layer 1: exact per-step recurrence, spikes recorded as 64-bit mask.
    float c[16], v[16];
    u32 blo[16], bhi[16];
#pragma unroll
    for (int u = 0; u < 16; ++u) {
        c[u] = acc[u >> 2][u & 3];
        v[u] = 0.f; blo[u] = 0u; bhi[u] = 0u;
    }
    for (int t = 0; t < 32; ++t) {
#pragma unroll
        for (int u = 0; u < 16; ++u) {
            v[u] += (c[u] - v[u]) * 0.5f;           // v += (c - v)/tau, tau=2
            bool s = v[u] >= 1.0f;                  // spike(v - 1) == (v >= 1)
            blo[u] |= (s ? 1u : 0u) << t;
            v[u] = s ? 0.f : v[u];                  // hard reset
        }
    }
    for (int t = 0; t < 32; ++t) {
#pragma unroll
        for (int u = 0; u < 16; ++u) {
            v[u] += (c[u] - v[u]) * 0.5f;
            bool s = v[u] >= 1.0f;
            bhi[u] |= (s ? 1u : 0u) << t;
            v[u] = s ? 0.f : v[u];
        }
    }
#pragma unroll
    for (int u = 0; u < 16; ++u) {
        int r = u >> 2, cc = u & 3;
        bits[(size_t)(bm + (ty << 2) + r) * N1 + (bn + (tx << 2) + cc)] =
            ((u64)bhi[u] << 32) | (u64)blo[u];
    }
}

// ---------------- K2: layer 2 fused: compact -> gather weights to LDS -> c2 -> LIF-2 -> out ----
// 1 batch/block, 4 waves x 256-j segments. Active weight rows gathered into LDS in one
// parallel round trip; phase 2 reads weights via LDS broadcast. No cross-wave sync until
// the final reduce. LIF-2 tail with 8-deep batched c2 reads.
__global__ __launch_bounds__(256) void k_c2lif(
    const u64* __restrict__ bits, const float* __restrict__ W2T,
    float* __restrict__ out)
{
    __shared__ u64   masksS[N1];        // 8 KB
    __shared__ u32   idxS[N1];          // 4 KB
    __shared__ float wS[4][64][12];     // 12 KB gathered active weights (per region, 64/pass)
    __shared__ float c2S[4][64][12];    // 12 KB per-wave partials
    __shared__ float c2r[64][12];       // 3 KB reduced
    __shared__ float s2S[64][10];       // 2.5 KB

    const int tid  = threadIdx.x;
    const int w    = tid >> 6;      // wave = j-segment
    const int lane = tid & 63;      // = timestep in phase 2
    const int b    = blockIdx.x;

    const u64* row = bits + (size_t)b * N1;
    const int base_j = w << 8;

    // ---- phase 1: scan + ballot-compact this wave's 256-j segment ----
    u64 mm[4];
#pragma unroll
    for (int q = 0; q < 4; ++q) mm[q] = row[base_j + (q << 6) + lane];

    int nact = 0;
#pragma unroll
    for (int q = 0; q < 4; ++q) {
        u64 ball = __ballot(mm[q] != 0ULL);
        int pos = nact + __popcll(ball & ((1ULL << lane) - 1ULL));
        if (mm[q] != 0ULL) { masksS[base_j + pos] = mm[q]; idxS[base_j + pos] = base_j + (q << 6) + lane; }
        nact += __popcll(ball);
    }
    // zero-pad to multiple of 4 (mask=0 entries are exact no-ops)
    const int npad = (nact + 3) & ~3;
    if (lane < npad - nact) { masksS[base_j + nact + lane] = 0ULL; idxS[base_j + nact + lane] = 0u; }
    asm volatile("s_waitcnt lgkmcnt(0)" ::: "memory");

    float acc[10];
#pragma unroll
    for (int i = 0; i < 10; ++i) acc[i] = 0.f;

    // ---- passes of up to 64 entries: gather weights (1 round trip), then dense FMA ----
    for (int base = 0; base < npad; base += 64) {
        const int cnt = min(64, npad - base);
        if (lane < cnt) {                       // lane e gathers weight row of entry base+e
            int j = (int)idxS[base_j + base + lane];
            const float4* src = (const float4*)(W2T + j * 12);
            float4 a = src[0], bq = src[1], cq = src[2];
            *(float4*)&wS[w][lane][0] = a;
            *(float4*)&wS[w][lane][4] = bq;
            *(float4*)&wS[w][lane][8] = cq;
        }
        asm volatile("s_waitcnt lgkmcnt(0) vmcnt(0)" ::: "memory");
        __builtin_amdgcn_sched_barrier(0);

        for (int a = 0; a < cnt; a += 4) {
            u64 m[4];
#pragma unroll
            for (int q = 0; q < 4; ++q) m[q] = masksS[base_j + base + a + q];
#pragma unroll
            for (int q = 0; q < 4; ++q) {
                float sf = (float)((m[q] >> lane) & 1ULL);
                const float* wr = &wS[w][a + q][0];     // uniform addr -> LDS broadcast
                float4 w0 = *(const float4*)(wr);
                float4 w1 = *(const float4*)(wr + 4);
                float2 w2 = *(const float2*)(wr + 8);
                acc[0] = fmaf(sf, w0.x, acc[0]); acc[1] = fmaf(sf, w0.y, acc[1]);
                acc[2] = fmaf(sf, w0.z, acc[2]); acc[3] = fmaf(sf, w0.w, acc[3]);
                acc[4] = fmaf(sf, w1.x, acc[4]); acc[5] = fmaf(sf, w1.y, acc[5]);
                acc[6] = fmaf(sf, w1.z, acc[6]); acc[7] = fmaf(sf, w1.w, acc[7]);
                acc[8] = fmaf(sf, w2.x, acc[8]); acc[9] = fmaf(sf, w2.y, acc[9]);
            }
        }
    }

#pragma unroll
    for (int i = 0; i < 10; ++i) c2S[w][lane][i] = acc[i];
    __syncthreads();

    // ---- reduce 4 partials into c2r (same add order as before) ----
    for (int idx = tid; idx < 64 * 10; idx += 256) {
        int t = idx / 10, i = idx % 10;
        c2r[t][i] = ((c2S[0][t][i] + c2S[1][t][i]) + c2S[2][t][i]) + c2S[3][t][i];
    }
    __syncthreads();

    // ---- LIF layer 2: 10 threads, 8-deep batched c2 reads ----
    if (tid < 10) {
        const int i = tid;
        float v2 = 0.f;
        for (int tb = 0; tb < 64; tb += 8) {
            float cc[8];
#pragma unroll
            for (int q = 0; q < 8; ++q) cc[q] = c2r[tb + q][i];   // 8 LDS reads in flight
#pragma unroll
            for (int q = 0; q < 8; ++q) {
                v2 += (cc[q] - v2) * 0.5f;
                bool s = v2 >= 1.0f;
                s2S[tb + q][i] = s ? 1.f : 0.f;
                v2 = s ? 0.f : v2;
            }
        }
    }
    __syncthreads();

    // ---- write out[t][b][0..9] ----
    for (int idx = tid; idx < 64 * 10; idx += 256) {
        int t = idx / 10, i = idx % 10;
        out[(size_t)t * (NB * N2) + (size_t)b * N2 + i] = s2S[t][i];
    }
}

extern "C" void kernel_launch(void* const* d_in, const int* in_sizes, int n_in,
                              void* d_out, int out_size, void* d_ws, size_t ws_size,
                              hipStream_t stream) {
    const float* X  = (const float*)d_in[0];   // [2048, 784]
    const float* W1 = (const float*)d_in[1];   // [1024, 784]
    const float* W2 = (const float*)d_in[2];   // [10, 1024]
    float* out = (float*)d_out;                // [64, 2048, 10]

    char* ws = (char*)d_ws;
    u64*   bits = (u64*)ws;                                   // 16 MiB
    float* W2T  = (float*)(ws + (size_t)NB * N1 * 8);         // 48 KiB
    float* Xt   = (float*)(ws + (size_t)NB * N1 * 8 + 65536); // 6.27 MiB
    float* W1t  = Xt + (size_t)KDIM * NB;                     // 3.14 MiB

    k_prep<<<dim3(2401), dim3(256), 0, stream>>>(X, Xt, W1, W1t, W2, W2T);

    dim3 g1(N1 / 64, NB / 64);   // (16, 32)
    k_gemm_lif1<<<g1, dim3(256), 0, stream>>>(Xt, W1t, bits);

    k_c2lif<<<dim3(NB), dim3(256), 0, stream>>>(bits, W2T, out);
}

// Round 10
// 201.508 us; speedup vs baseline: 1.0014x; 1.0014x over previous
//
#include <hip/hip_runtime.h>
#include <stdint.h>

typedef unsigned long long u64;
typedef unsigned int u32;

#define T_STEPS 64
#define KDIM 784
#define N1 1024
#define NB 2048
#define N2 10

// ---------------- K0: fused prep: transposes X->Xt, W1->W1t, and W2->W2T ----------------
// blocks 0..1599: X tiles; 1600..2399: W1 tiles; 2400: W2T.
__global__ __launch_bounds__(256) void k_prep(
    const float* __restrict__ X, float* __restrict__ Xt,
    const float* __restrict__ W1, float* __restrict__ W1t,
    const float* __restrict__ W2, float* __restrict__ W2T)
{
    int b = blockIdx.x;
    if (b == 2400) {                     // W2 [10][1024] -> W2T [1024][12]
        for (int it = 0; it < 4; ++it) {
            int j = it * 256 + threadIdx.x;
            float r[12];
#pragma unroll
            for (int i = 0; i < 10; ++i) r[i] = W2[i * N1 + j];
            r[10] = 0.f; r[11] = 0.f;
#pragma unroll
            for (int i = 0; i < 12; ++i) W2T[j * 12 + i] = r[i];
        }
        return;
    }
    __shared__ float t[32][33];
    const float* src; float* dst; int R;
    int tile_r, tile_c;
    if (b < 1600) { src = X;  dst = Xt;  R = NB; tile_r = b / 25; tile_c = b % 25; }
    else { b -= 1600; src = W1; dst = W1t; R = N1; tile_r = b / 25; tile_c = b % 25; }

    const int tx = threadIdx.x & 31, ty = threadIdx.x >> 5;
    const int r0 = tile_r << 5, c0 = tile_c << 5;

#pragma unroll
    for (int i = 0; i < 32; i += 8) {
        int c = c0 + tx;
        t[ty + i][tx] = (c < KDIM) ? src[(size_t)(r0 + ty + i) * KDIM + c] : 0.f;
    }
    __syncthreads();
#pragma unroll
    for (int i = 0; i < 32; i += 8) {
        int c = c0 + ty + i;
        if (c < KDIM) dst[(size_t)c * R + r0 + tx] = t[tx][ty + i];
    }
}

// ---------------- K1: c1 = X @ W1^T (fp32), 4-buffer counted-vmcnt glds pipeline, ----------
// ---------------- tile loop unrolled x4 so the LDS buffer index is a literal  ----------
// 64x64 tile, 256 threads, 4x4/thread. glds w16 staging, prefetch depth 2,
// s_waitcnt vmcnt(2) steady state; vmcnt(0) only on the peeled final tile.
// FMA order: k ascending sequential per accumulator -> c1 bit-identical.
#define NSTEP (KDIM / 16)   // 49

typedef const __attribute__((address_space(1))) void gas_void;
typedef __attribute__((address_space(3))) void las_void;

__global__ __launch_bounds__(256) void k_gemm_lif1(
    const float* __restrict__ Xt,    // [784][2048]
    const float* __restrict__ W1t,   // [784][1024]
    u64* __restrict__ bits)
{
    __shared__ __align__(16) float A2[4][16][64];   // 16 KB
    __shared__ __align__(16) float B2[4][16][64];   // 16 KB

    const int tid  = threadIdx.x;
    const int lane = tid & 63;
    const int tx   = tid & 15;             // n-group
    const int ty   = tid >> 4;             // m-group (0..15)
    const int bm   = blockIdx.y << 6;
    const int bn   = blockIdx.x << 6;

    // staging: wave w owns rows 4w..4w+3 of each 16x64 tile (A and B)
    const int w4   = __builtin_amdgcn_readfirstlane((tid >> 6) << 2);
    const int srow = w4 + (lane >> 4);
    const int scol = (lane & 15) << 2;

    const float* gA = Xt  + (size_t)srow * NB + bm + scol;
    const float* gB = W1t + (size_t)srow * N1 + bn + scol;

#define STAGE(pp, t)                                                          \
    {                                                                         \
        __builtin_amdgcn_global_load_lds((gas_void*)(gA + (size_t)(t) * (16 * NB)), \
                                         (las_void*)&A2[pp][w4][0], 16, 0, 0); \
        __builtin_amdgcn_global_load_lds((gas_void*)(gB + (size_t)(t) * (16 * N1)), \
                                         (las_void*)&B2[pp][w4][0], 16, 0, 0); \
    }

#define COMPUTE(CUR)                                                          \
    _Pragma("unroll")                                                         \
    for (int kk = 0; kk < 16; ++kk) {                                         \
        float4 av = *(const float4*)(&A2[CUR][kk][ty << 2]);                  \
        float4 bv = *(const float4*)(&B2[CUR][kk][tx << 2]);                  \
        acc[0][0] = fmaf(av.x, bv.x, acc[0][0]); acc[0][1] = fmaf(av.x, bv.y, acc[0][1]); \
        acc[0][2] = fmaf(av.x, bv.z, acc[0][2]); acc[0][3] = fmaf(av.x, bv.w, acc[0][3]); \
        acc[1][0] = fmaf(av.y, bv.x, acc[1][0]); acc[1][1] = fmaf(av.y, bv.y, acc[1][1]); \
        acc[1][2] = fmaf(av.y, bv.z, acc[1][2]); acc[1][3] = fmaf(av.y, bv.w, acc[1][3]); \
        acc[2][0] = fmaf(av.z, bv.x, acc[2][0]); acc[2][1] = fmaf(av.z, bv.y, acc[2][1]); \
        acc[2][2] = fmaf(av.z, bv.z, acc[2][2]); acc[2][3] = fmaf(av.z, bv.w, acc[2][3]); \
        acc[3][0] = fmaf(av.w, bv.x, acc[3][0]); acc[3][1] = fmaf(av.w, bv.y, acc[3][1]); \
        acc[3][2] = fmaf(av.w, bv.z, acc[3][2]); acc[3][3] = fmaf(av.w, bv.w, acc[3][3]); \
    }

    // One body: wait for tile T's staging (2 newest ops = stage T+1 in flight),
    // barrier, issue stage T+2 into literal buffer (U+2)&3, compute literal buffer U.
#define BODY(T, U)                                                            \
    {                                                                         \
        asm volatile("s_waitcnt vmcnt(2)" ::: "memory");                      \
        __builtin_amdgcn_sched_barrier(0);                                    \
        __builtin_amdgcn_s_barrier();                                         \
        __builtin_amdgcn_sched_barrier(0);                                    \
        if ((T) + 2 < NSTEP) STAGE(((U) + 2) & 3, (T) + 2);                   \
        __builtin_amdgcn_sched_barrier(0);                                    \
        COMPUTE((U));                                                         \
        __builtin_amdgcn_sched_barrier(0);                                    \
    }

    float acc[4][4];
#pragma unroll
    for (int r = 0; r < 4; ++r)
#pragma unroll
        for (int c = 0; c < 4; ++c) acc[r][c] = 0.f;

    // prologue: 2 stages in flight
    STAGE(0, 0);
    STAGE(1, 1);

    for (int tt = 0; tt < 12; ++tt) {       // tiles 0..47, buffer index literal per body
        const int t0 = tt << 2;
        BODY(t0 + 0, 0);
        BODY(t0 + 1, 1);
        BODY(t0 + 2, 2);
        BODY(t0 + 3, 3);
    }
    // peeled tile 48 (buffer 0): full drain
    asm volatile("s_waitcnt vmcnt(0)" ::: "memory");
    __builtin_amdgcn_sched_barrier(0);
    __builtin_amdgcn_s_barrier();
    __builtin_amdgcn_sched_barrier(0);
    COMPUTE(0);
#undef BODY
#undef STAGE
#undef COMPUTE

    // LIF layer 1: exact per-step recurrence, spikes recorded as 64-bit mask.
    float c[16], v[16];
    u32 blo[16], bhi[16];
#pragma unroll
    for (int u = 0; u < 16; ++u) {
        c[u] = acc[u >> 2][u & 3];
        v[u] = 0.f; blo[u] = 0u; bhi[u] = 0u;
    }
    for (int t = 0; t < 32; ++t) {
#pragma unroll
        for (int u = 0; u < 16; ++u) {
            v[u] += (c[u] - v[u]) * 0.5f;           // v += (c - v)/tau, tau=2
            bool s = v[u] >= 1.0f;                  // spike(v - 1) == (v >= 1)
            blo[u] |= (s ? 1u : 0u) << t;
            v[u] = s ? 0.f : v[u];                  // hard reset
        }
    }
    for (int t = 0; t < 32; ++t) {
#pragma unroll
        for (int u = 0; u < 16; ++u) {
            v[u] += (c[u] - v[u]) * 0.5f;
            bool s = v[u] >= 1.0f;
            bhi[u] |= (s ? 1u : 0u) << t;
            v[u] = s ? 0.f : v[u];
        }
    }
#pragma unroll
    for (int u = 0; u < 16; ++u) {
        int r = u >> 2, cc = u & 3;
        bits[(size_t)(bm + (ty << 2) + r) * N1 + (bn + (tx << 2) + cc)] =
            ((u64)bhi[u] << 32) | (u64)blo[u];
    }
}

// ---------------- K2: layer 2 fused: compact -> gather weights to LDS -> c2 -> LIF-2 -> out ----
// 1 batch/block, 4 waves x 256-j segments. Active weight rows gathered into LDS in one
// parallel round trip; phase 2 reads weights via LDS broadcast. No cross-wave sync until
// the final reduce. LIF-2 tail with 8-deep batched c2 reads.
__global__ __launch_bounds__(256) void k_c2lif(
    const u64* __restrict__ bits, const float* __restrict__ W2T,
    float* __restrict__ out)
{
    __shared__ u64   masksS[N1];        // 8 KB
    __shared__ u32   idxS[N1];          // 4 KB
    __shared__ float wS[4][64][12];     // 12 KB gathered active weights (per region, 64/pass)
    __shared__ float c2S[4][64][12];    // 12 KB per-wave partials
    __shared__ float c2r[64][12];       // 3 KB reduced
    __shared__ float s2S[64][10];       // 2.5 KB

    const int tid  = threadIdx.x;
    const int w    = tid >> 6;      // wave = j-segment
    const int lane = tid & 63;      // = timestep in phase 2
    const int b    = blockIdx.x;

    const u64* row = bits + (size_t)b * N1;
    const int base_j = w << 8;

    // ---- phase 1: scan + ballot-compact this wave's 256-j segment ----
    u64 mm[4];
#pragma unroll
    for (int q = 0; q < 4; ++q) mm[q] = row[base_j + (q << 6) + lane];

    int nact = 0;
#pragma unroll
    for (int q = 0; q < 4; ++q) {
        u64 ball = __ballot(mm[q] != 0ULL);
        int pos = nact + __popcll(ball & ((1ULL << lane) - 1ULL));
        if (mm[q] != 0ULL) { masksS[base_j + pos] = mm[q]; idxS[base_j + pos] = base_j + (q << 6) + lane; }
        nact += __popcll(ball);
    }
    // zero-pad to multiple of 4 (mask=0 entries are exact no-ops)
    const int npad = (nact + 3) & ~3;
    if (lane < npad - nact) { masksS[base_j + nact + lane] = 0ULL; idxS[base_j + nact + lane] = 0u; }
    asm volatile("s_waitcnt lgkmcnt(0)" ::: "memory");

    float acc[10];
#pragma unroll
    for (int i = 0; i < 10; ++i) acc[i] = 0.f;

    // ---- passes of up to 64 entries: gather weights (1 round trip), then dense FMA ----
    for (int base = 0; base < npad; base += 64) {
        const int cnt = min(64, npad - base);
        if (lane < cnt) {                       // lane e gathers weight row of entry base+e
            int j = (int)idxS[base_j + base + lane];
            const float4* src = (const float4*)(W2T + j * 12);
            float4 a = src[0], bq = src[1], cq = src[2];
            *(float4*)&wS[w][lane][0] = a;
            *(float4*)&wS[w][lane][4] = bq;
            *(float4*)&wS[w][lane][8] = cq;
        }
        asm volatile("s_waitcnt lgkmcnt(0) vmcnt(0)" ::: "memory");
        __builtin_amdgcn_sched_barrier(0);

        for (int a = 0; a < cnt; a += 4) {
            u64 m[4];
#pragma unroll
            for (int q = 0; q < 4; ++q) m[q] = masksS[base_j + base + a + q];
#pragma unroll
            for (int q = 0; q < 4; ++q) {
                float sf = (float)((m[q] >> lane) & 1ULL);
                const float* wr = &wS[w][a + q][0];     // uniform addr -> LDS broadcast
                float4 w0 = *(const float4*)(wr);
                float4 w1 = *(const float4*)(wr + 4);
                float2 w2 = *(const float2*)(wr + 8);
                acc[0] = fmaf(sf, w0.x, acc[0]); acc[1] = fmaf(sf, w0.y, acc[1]);
                acc[2] = fmaf(sf, w0.z, acc[2]); acc[3] = fmaf(sf, w0.w, acc[3]);
                acc[4] = fmaf(sf, w1.x, acc[4]); acc[5] = fmaf(sf, w1.y, acc[5]);
                acc[6] = fmaf(sf, w1.z, acc[6]); acc[7] = fmaf(sf, w1.w, acc[7]);
                acc[8] = fmaf(sf, w2.x, acc[8]); acc[9] = fmaf(sf, w2.y, acc[9]);
            }
        }
    }

#pragma unroll
    for (int i = 0; i < 10; ++i) c2S[w][lane][i] = acc[i];
    __syncthreads();

    // ---- reduce 4 partials into c2r (same add order as before) ----
    for (int idx = tid; idx < 64 * 10; idx += 256) {
        int t = idx / 10, i = idx % 10;
        c2r[t][i] = ((c2S[0][t][i] + c2S[1][t][i]) + c2S[2][t][i]) + c2S[3][t][i];
    }
    __syncthreads();

    // ---- LIF layer 2: 10 threads, 8-deep batched c2 reads ----
    if (tid < 10) {
        const int i = tid;
        float v2 = 0.f;
        for (int tb = 0; tb < 64; tb += 8) {
            float cc[8];
#pragma unroll
            for (int q = 0; q < 8; ++q) cc[q] = c2r[tb + q][i];   // 8 LDS reads in flight
#pragma unroll
            for (int q = 0; q < 8; ++q) {
                v2 += (cc[q] - v2) * 0.5f;
                bool s = v2 >= 1.0f;
                s2S[tb + q][i] = s ? 1.f : 0.f;
                v2 = s ? 0.f : v2;
            }
        }
    }
    __syncthreads();

    // ---- write out[t][b][0..9] ----
    for (int idx = tid; idx < 64 * 10; idx += 256) {
        int t = idx / 10, i = idx % 10;
        out[(size_t)t * (NB * N2) + (size_t)b * N2 + i] = s2S[t][i];
    }
}

extern "C" void kernel_launch(void* const* d_in, const int* in_sizes, int n_in,
                              void* d_out, int out_size, void* d_ws, size_t ws_size,
                              hipStream_t stream) {
    const float* X  = (const float*)d_in[0];   // [2048, 784]
    const float* W1 = (const float*)d_in[1];   // [1024, 784]
    const float* W2 = (const float*)d_in[2];   // [10, 1024]
    float* out = (float*)d_out;                // [64, 2048, 10]

    char* ws = (char*)d_ws;
    u64*   bits = (u64*)ws;                                   // 16 MiB
    float* W2T  = (float*)(ws + (size_t)NB * N1 * 8);         // 48 KiB
    float* Xt   = (float*)(ws + (size_t)NB * N1 * 8 + 65536); // 6.27 MiB
    float* W1t  = Xt + (size_t)KDIM * NB;                     // 3.14 MiB

    k_prep<<<dim3(2401), dim3(256), 0, stream>>>(X, Xt, W1, W1t, W2, W2T);

    dim3 g1(N1 / 64, NB / 64);   // (16, 32)
    k_gemm_lif1<<<g1, dim3(256), 0, stream>>>(Xt, W1t, bits);

    k_c2lif<<<dim3(NB), dim3(256), 0, stream>>>(bits, W2T, out);
}